// Round 1
// baseline (869.281 us; speedup 1.0000x reference)
//
#include <hip/hip_runtime.h>
#include <stdint.h>
#include <stddef.h>

// Problem constants
#define S_LEN 128
#define B_SZ  64
#define V_SZ  32000
#define EH    512
#define EO    512
#define H_SZ  1024
#define O_SZ  1024
#define G3    3072   // 3*H

typedef __attribute__((ext_vector_type(8))) short short8;
typedef __attribute__((ext_vector_type(4))) float floatx4;
typedef __attribute__((ext_vector_type(8))) unsigned short ushortx8;
typedef __attribute__((ext_vector_type(4))) unsigned uintx4;

__device__ __forceinline__ unsigned short f2bf(float f) {
  unsigned u = __builtin_bit_cast(unsigned, f);
  u += 0x7FFFu + ((u >> 16) & 1u);   // round-to-nearest-even
  return (unsigned short)(u >> 16);
}
__device__ __forceinline__ float bf2f(unsigned short h) {
  unsigned u = ((unsigned)h) << 16;
  return __builtin_bit_cast(float, u);
}

__device__ __forceinline__ void gld_lds16(const void* g, void* l) {
  __builtin_amdgcn_global_load_lds((const __attribute__((address_space(1))) void*)g,
                                   (__attribute__((address_space(3))) void*)l, 16, 0, 0);
}

// ---------------------------------------------------------------- converts
// Fused fp32->bf16 convert of W2 / W_ih / W_out into ONE contiguous output
// region (W2b | Wihb | Woutb are allocated back-to-back, sizes all multiples
// of 256 B so there is no padding gap). Saves 2 kernel launches.
__global__ __launch_bounds__(256) void cvt3_bf16(const float* __restrict__ a,
                                                 const float* __restrict__ b,
                                                 const float* __restrict__ c,
                                                 unsigned short* __restrict__ out) {
  const int na4 = (EO * EH) / 4;        // 65536
  const int nb4 = (G3 * EO) / 4;        // 393216
  int i = blockIdx.x * 256 + threadIdx.x;   // grid sized exactly: 720896 total
  const float* src;
  int off;
  if (i < na4)            { src = a; off = i; }
  else if (i < na4 + nb4) { src = b; off = i - na4; }
  else                    { src = c; off = i - na4 - nb4; }
  float4 v = ((const float4*)src)[off];
  ushort4 o;
  o.x = f2bf(v.x); o.y = f2bf(v.y); o.z = f2bf(v.z); o.w = f2bf(v.w);
  ((ushort4*)out)[i] = o;
}

// ------------------------------------------------- W1 [EH][V] -> W1T bf16 [V][EH]
__global__ __launch_bounds__(256) void transpose_w1_bf16(const float* __restrict__ W1,
                                                         unsigned short* __restrict__ W1T) {
  __shared__ unsigned short tile[64][72];   // [v][e], padded
  int t = threadIdx.x;
  int v0 = blockIdx.x * 64;
  int e0 = blockIdx.y * 64;
  for (int i = 0; i < 4; ++i) {
    int e = (t >> 4) + i * 16;
    int v = (t & 15) * 4;
    float4 w = *(const float4*)&W1[(size_t)(e0 + e) * V_SZ + v0 + v];
    tile[v + 0][e] = f2bf(w.x);
    tile[v + 1][e] = f2bf(w.y);
    tile[v + 2][e] = f2bf(w.z);
    tile[v + 3][e] = f2bf(w.w);
  }
  __syncthreads();
  for (int i = 0; i < 2; ++i) {
    int v = (t >> 3) + i * 32;
    int e = (t & 7) * 8;
    ushortx8 o;
    for (int j = 0; j < 8; ++j) o[j] = tile[v][e + j];
    *(ushortx8*)&W1T[(size_t)(v0 + v) * EH + e0 + e] = o;
  }
}

// ------------------------------------------------- gather + b1 + threshold -> emb bf16
__global__ __launch_bounds__(256) void gather_emb(const int* __restrict__ ids,
                                                  const unsigned short* __restrict__ W1T,
                                                  const float* __restrict__ b1,
                                                  unsigned short* __restrict__ emb) {
  int t = threadIdx.x;
  int tok = blockIdx.x * 4 + (t >> 6);
  int lane = t & 63;
  int id = ids[tok];
  ushortx8 w = *(const ushortx8*)&W1T[(size_t)id * EH + lane * 8];
  float4 blo = *(const float4*)&b1[lane * 8];
  float4 bhi = *(const float4*)&b1[lane * 8 + 4];
  float bv[8] = {blo.x, blo.y, blo.z, blo.w, bhi.x, bhi.y, bhi.z, bhi.w};
  ushortx8 o;
  for (int j = 0; j < 8; ++j) {
    float x = bf2f(w[j]) + bv[j];
    x = (x > 1e-6f) ? x : 0.0f;
    o[j] = f2bf(x);
  }
  *(ushortx8*)&emb[(size_t)tok * EH + lane * 8] = o;
}

// ------------------------------------------------- MFMA GEMM, C = act(A @ B^T + bias)
template <int ACT, int OUT_BF16>
__global__ __launch_bounds__(256) void gemm_bt(const unsigned short* __restrict__ A,
                                               const unsigned short* __restrict__ B,
                                               const float* __restrict__ bias,
                                               void* __restrict__ Cout,
                                               int M, int N, int K) {
  __shared__ unsigned short lA[128 * 32];
  __shared__ unsigned short lB[128 * 32];
  int t = threadIdx.x;
  int lane = t & 63;
  int wave = t >> 6;
  int bn = blockIdx.x, bm = blockIdx.y;
  int wm = (wave >> 1) * 64;
  int wn = (wave & 1) * 64;
  floatx4 acc[4][4] = {};

  int arow = t >> 2;
  int acol = (t & 3) * 8;

  int ga0 = bm * 128 + arow;       if (ga0 >= M) ga0 = M - 1;
  int ga1 = bm * 128 + arow + 64;  if (ga1 >= M) ga1 = M - 1;
  const unsigned short* a0 = A + (size_t)ga0 * K + acol;
  const unsigned short* a1 = A + (size_t)ga1 * K + acol;
  const unsigned short* b0 = B + (size_t)(bn * 128 + arow) * K + acol;
  const unsigned short* b1 = B + (size_t)(bn * 128 + arow + 64) * K + acol;
  unsigned short* lA0 = &lA[t * 8];
  unsigned short* lA1 = &lA[t * 8 + 64 * 32];
  unsigned short* lB0 = &lB[t * 8];
  unsigned short* lB1 = &lB[t * 8 + 64 * 32];

  for (int k0 = 0; k0 < K; k0 += 32) {
    __syncthreads();
    gld_lds16(a0 + k0, lA0);
    gld_lds16(a1 + k0, lA1);
    gld_lds16(b0 + k0, lB0);
    gld_lds16(b1 + k0, lB1);
    __syncthreads();
    short8 af[4], bfr[4];
    for (int i = 0; i < 4; ++i)
      af[i] = *(const short8*)&lA[(wm + i * 16 + (lane & 15)) * 32 + (lane >> 4) * 8];
    for (int j = 0; j < 4; ++j)
      bfr[j] = *(const short8*)&lB[(wn + j * 16 + (lane & 15)) * 32 + (lane >> 4) * 8];
    for (int i = 0; i < 4; ++i)
      for (int j = 0; j < 4; ++j)
        acc[i][j] = __builtin_amdgcn_mfma_f32_16x16x32_bf16(af[i], bfr[j], acc[i][j], 0, 0, 0);
  }

  int rowq = (lane >> 4) * 4;
  for (int j = 0; j < 4; ++j) {
    int col = bn * 128 + wn + j * 16 + (lane & 15);
    float bv = bias[col];
    for (int i = 0; i < 4; ++i) {
      int row0 = bm * 128 + wm + i * 16 + rowq;
      for (int r = 0; r < 4; ++r) {
        int row = row0 + r;
        if (row < M) {
          float v = acc[i][j][r] + bv;
          if (ACT) v = (v > 1e-6f) ? v : 0.0f;
          if (OUT_BF16) ((unsigned short*)Cout)[(size_t)row * N + col] = f2bf(v);
          else          ((float*)Cout)[(size_t)row * N + col] = v;
        }
      }
    }
  }
}

// ------------------------------------------------- W_hh fp32 [3H][H] -> Wprep bf16 in
// MFMA-B-fragment order (see gru_persist).
__global__ __launch_bounds__(256) void prep_whh(const float* __restrict__ W_hh,
                                                unsigned short* __restrict__ Wprep) {
  int tid = blockIdx.x * 256 + threadIdx.x;   // 393216 total
  int lane = tid & 63;
  int c = tid >> 6;          // chunk 0..6143
  int cg = c / 96;
  int r  = c % 96;
  int g  = r >> 5;
  int t  = r & 31;
  int row = g * H_SZ + cg * 16 + (lane & 15);
  int k   = t * 32 + (lane >> 4) * 8;
  const float* src = &W_hh[(size_t)row * H_SZ + k];
  float4 v0 = *(const float4*)src;
  float4 v1 = *(const float4*)(src + 4);
  ushortx8 o;
  o[0] = f2bf(v0.x); o[1] = f2bf(v0.y); o[2] = f2bf(v0.z); o[3] = f2bf(v0.w);
  o[4] = f2bf(v1.x); o[5] = f2bf(v1.y); o[6] = f2bf(v1.z); o[7] = f2bf(v1.w);
  ((ushortx8*)Wprep)[tid] = o;
}

// ------------------------------------------------- persistent GRU recurrence
// 256 blocks x 256 threads, cooperative. Block (bg,cg): batches [bg*16,+16),
// h-cols [cg*16,+16), all 3 gates; wave w = K-quarter [w*256,+256).
//
// DECENTRALIZED PER-WAVE FLAG BARRIER (replaces the centralized fetch_add
// counter: 64 serialized same-address atomics + s_sleep quantization + release
// barrier were the bulk of the 3.0us/step):
//  - producer: each wave drains ONLY its own h-stores (s_waitcnt vmcnt(0)),
//    lane0 stores flags[bg][cg][w] = s+1. No block barrier, no contention.
//  - consumer: wave w needs h cols [256w,+256) = producers cg in [16w,+16)
//    x 4 waves = 64 flags = ONE coalesced wave64 load per poll (256 B,
//    contiguous, broadcast-friendly at L3). Spin until all lanes satisfied.
// Safety: a wave's flag s+1 implies its step-s loads completed (loads are
// vmcnt-tied before its stores/flag). A block's step-(s+1) h-stores happen
// after its mid-step __syncthreads, which joins all 4 waves whose polls
// collectively cover ALL 256 wave-flags of the bg -> writer-after-reader on
// the double-buffered h is safe. lgh is parity double-buffered because the
// end-of-step block barrier that used to protect it is gone.
__global__ __launch_bounds__(256) void gru_persist(const unsigned short* __restrict__ hprep0,
                                                   unsigned short* __restrict__ hprep1,
                                                   unsigned short* __restrict__ hbfinal,
                                                   const unsigned short* __restrict__ Wprep,
                                                   const float* __restrict__ b_hh,
                                                   const unsigned short* __restrict__ xW,
                                                   unsigned* __restrict__ flags) {
  __shared__ unsigned short lB[96 * 512];   // 98304 B : W_hh slice, fragment order
  __shared__ float lgh[2][3][4][256];       // 24576 B : per-wave K-partials, step-parity dbuf
  int t = threadIdx.x;
  int lane = t & 63;
  int w = t >> 6;
  int bg = blockIdx.x >> 6;    // 0..3
  int cg = blockIdx.x & 63;    // 0..63

  // stage W_hh slice once (identity copy, 98 KB)
  const unsigned short* wsrc = Wprep + (size_t)cg * 96 * 512;
  for (int i = 0; i < 24; ++i) {
    int c = w * 24 + i;
    gld_lds16(wsrc + (size_t)c * 512 + lane * 8, &lB[c * 512 + lane * 8]);
  }

  // per-thread update-element constants
  int b_loc = t >> 4;
  int j_loc = t & 15;
  int jcol = cg * 16 + j_loc;          // h column
  int bglob = bg * 16 + b_loc;         // batch
  float bhr = b_hh[jcol];
  float bhz = b_hh[H_SZ + jcol];
  float bhn = b_hh[2 * H_SZ + jcol];
  // scatter-store position for h_new (A-fragment layout); lane pairs (jj even/odd)
  // pack 2 bf16 into one dword store.
  int tt2 = jcol >> 5;
  int q   = (jcol >> 3) & 3;
  int jj  = jcol & 7;
  int Ls  = b_loc | (q << 4);
  size_t hw_off32 = ((((size_t)(bg * 32 + tt2) * 64 + Ls) * 8) + (jj & ~1)) >> 1;

  // flag layout: flags[bg*256 + cg*4 + wv]  (u32 each, 4 KiB total)
  unsigned* fstore = flags + bg * 256 + cg * 4 + w;
  // wave w polls producers cg' in [16w,+16) x waves [0,4):
  // index bg*256 + (16w + lane/4)*4 + (lane&3) == bg*256 + w*64 + lane
  const unsigned* fpoll = flags + bg * 256 + w * 64 + lane;

  float hmaster = 0.0f;                // fp32 master h for my (batch, col)
  const unsigned short* hbufs[2] = {hprep0, hprep1};
  __syncthreads();   // drains staging vmcnt

  for (int s = 0; s < S_LEN; ++s) {
    const unsigned short* hr = hbufs[s & 1];
    unsigned* hw32 = (unsigned*)hbufs[(s + 1) & 1];

    // A-fragments for my K-quarter: 8 x 16B coherent (sc1) loads, pipelined,
    // one tied waitcnt. Bypasses stale L1/L2 without any cache-wide inv.
    uintx4 av[8];
#pragma unroll
    for (int i = 0; i < 8; ++i) {
      int tt = w * 8 + i;
      const void* ap = hr + ((size_t)(bg * 32 + tt) * 64 + lane) * 8;
      asm volatile("global_load_dwordx4 %0, %1, off sc1" : "=v"(av[i]) : "v"(ap));
    }
    // xw loads (plain cached; produced before kernel launch)
    const unsigned short* xs = xW + (size_t)s * B_SZ * G3 + (size_t)bglob * G3;
    float xr = bf2f(xs[jcol]);
    float xz = bf2f(xs[H_SZ + jcol]);
    float xn = bf2f(xs[2 * H_SZ + jcol]);
    asm volatile("s_waitcnt vmcnt(0)"
                 : "+v"(av[0]), "+v"(av[1]), "+v"(av[2]), "+v"(av[3]),
                   "+v"(av[4]), "+v"(av[5]), "+v"(av[6]), "+v"(av[7])
                 :: "memory");

    floatx4 acc[3] = {};
#pragma unroll
    for (int i = 0; i < 8; ++i) {
      int tt = w * 8 + i;
      short8 a = __builtin_bit_cast(short8, av[i]);
#pragma unroll
      for (int g = 0; g < 3; ++g) {
        short8 bfr = *(const short8*)&lB[((g * 32 + tt) * 64 + lane) * 8];
        acc[g] = __builtin_amdgcn_mfma_f32_16x16x32_bf16(a, bfr, acc[g], 0, 0, 0);
      }
    }
    int par = s & 1;
#pragma unroll
    for (int g = 0; g < 3; ++g)
#pragma unroll
      for (int r = 0; r < 4; ++r)
        lgh[par][g][w][((lane >> 4) * 4 + r) * 16 + (lane & 15)] = acc[g][r];
    __syncthreads();   // joins all 4 waves: their polls cover ALL 256 wave-flags

    // gate update for my element (sum 4 K-partials)
    float ghr = lgh[par][0][0][t] + lgh[par][0][1][t] + lgh[par][0][2][t] + lgh[par][0][3][t] + bhr;
    float ghz = lgh[par][1][0][t] + lgh[par][1][1][t] + lgh[par][1][2][t] + lgh[par][1][3][t] + bhz;
    float ghn = lgh[par][2][0][t] + lgh[par][2][1][t] + lgh[par][2][2][t] + lgh[par][2][3][t] + bhn;
    float rr = 1.0f / (1.0f + __expf(-(xr + ghr)));
    float zz = 1.0f / (1.0f + __expf(-(xz + ghz)));
    float nn = tanhf(xn + rr * ghn);
    float hnew = (1.0f - zz) * nn + zz * hmaster;
    hmaster = hnew;

    unsigned hb = (unsigned)f2bf(hnew);
    unsigned other = (unsigned)__shfl_xor((int)hb, 1);
    if ((jj & 1) == 0) {
      unsigned packed = hb | (other << 16);   // (jj, jj+1)
      __hip_atomic_store(hw32 + hw_off32, packed,
                         __ATOMIC_RELAXED, __HIP_MEMORY_SCOPE_AGENT);
    }

    if (s == S_LEN - 1) {
      hbfinal[(size_t)bglob * H_SZ + jcol] = (unsigned short)hb;
    } else {
      // per-wave arrive: drain MY stores only, then publish my wave-flag
      asm volatile("s_waitcnt vmcnt(0)" ::: "memory");
      if (lane == 0)
        __hip_atomic_store(fstore, (unsigned)(s + 1),
                           __ATOMIC_RELAXED, __HIP_MEMORY_SCOPE_AGENT);
      // per-wave wait: one coalesced 64-flag load per iteration; lanes exit
      // independently via exec-mask, wave reconverges at loop end.
      unsigned tgt = (unsigned)(s + 1);
      while (__hip_atomic_load(fpoll, __ATOMIC_RELAXED,
                               __HIP_MEMORY_SCOPE_AGENT) < tgt) {}
    }
  }
}

// ----------------------------------------------------------------- launch
extern "C" void kernel_launch(void* const* d_in, const int* in_sizes, int n_in,
                              void* d_out, int out_size, void* d_ws, size_t ws_size,
                              hipStream_t stream) {
  const int*   ids   = (const int*)d_in[0];
  const float* W1    = (const float*)d_in[1];
  const float* b1    = (const float*)d_in[2];
  const float* W2    = (const float*)d_in[3];
  const float* b2    = (const float*)d_in[4];
  const float* W_ih  = (const float*)d_in[5];
  const float* b_ih  = (const float*)d_in[6];
  const float* W_hh  = (const float*)d_in[7];
  const float* b_hh  = (const float*)d_in[8];
  const float* W_out = (const float*)d_in[9];
  const float* b_out = (const float*)d_in[10];
  float* out = (float*)d_out;

  uint8_t* wsp = (uint8_t*)d_ws;
  auto alloc = [&](size_t bytes) {
    uint8_t* p = wsp;
    wsp += (bytes + 255) & ~(size_t)255;
    return p;
  };
  unsigned short* W1T   = (unsigned short*)alloc((size_t)V_SZ * EH * 2);
  // NOTE: W2b/Wihb/Woutb must stay contiguous & in this order (cvt3_bf16 fuses
  // all three converts into one launch over the concatenated region; all three
  // sizes are multiples of 256 B so alloc() inserts no padding between them).
  unsigned short* W2b   = (unsigned short*)alloc((size_t)EO * EH * 2);
  unsigned short* Wihb  = (unsigned short*)alloc((size_t)G3 * EO * 2);
  unsigned short* Woutb = (unsigned short*)alloc((size_t)O_SZ * H_SZ * 2);
  unsigned short* Wprep = (unsigned short*)alloc((size_t)G3 * H_SZ * 2);
  unsigned short* emb   = (unsigned short*)alloc((size_t)S_LEN * B_SZ * EH * 2);
  unsigned short* x     = (unsigned short*)alloc((size_t)S_LEN * B_SZ * EO * 2);
  unsigned short* xW    = (unsigned short*)alloc((size_t)S_LEN * B_SZ * G3 * 2);
  unsigned short* hprep0 = (unsigned short*)alloc((size_t)B_SZ * H_SZ * 2);
  unsigned short* hprep1 = (unsigned short*)alloc((size_t)B_SZ * H_SZ * 2);
  unsigned short* hbfinal = (unsigned short*)alloc((size_t)B_SZ * H_SZ * 2);
  unsigned*       flags   = (unsigned*)alloc(4096);   // [4 bg][64 cg][4 wave] u32

  // fused weight converts (fp32 -> bf16): W2 | W_ih | W_out -> one launch
  cvt3_bf16<<<dim3(2816), 256, 0, stream>>>(W2, W_ih, W_out, W2b);

  // W_hh -> MFMA-fragment-ordered bf16
  prep_whh<<<dim3(1536), 256, 0, stream>>>(W_hh, Wprep);

  // zero h0 (fragment-layout buffer read at s=0) and the wave-flag array
  hipMemsetAsync(hprep0, 0, (size_t)B_SZ * H_SZ * 2, stream);
  hipMemsetAsync(flags, 0, 4096, stream);

  // W1 transpose -> bf16
  transpose_w1_bf16<<<dim3(V_SZ / 64, EH / 64), 256, 0, stream>>>(W1, W1T);

  // embedding gather + b1 + threshold
  gather_emb<<<dim3(S_LEN * B_SZ / 4), 256, 0, stream>>>(ids, W1T, b1, emb);

  // x = thresh(emb @ W2^T + b2)
  gemm_bt<1, 1><<<dim3(EO / 128, S_LEN * B_SZ / 128), 256, 0, stream>>>(
      emb, W2b, b2, x, S_LEN * B_SZ, EO, EH);

  // xW = x @ W_ih^T + b_ih
  gemm_bt<0, 1><<<dim3(G3 / 128, S_LEN * B_SZ / 128), 256, 0, stream>>>(
      x, Wihb, b_ih, xW, S_LEN * B_SZ, G3, EO);

  // persistent GRU recurrence (cooperative: all 256 blocks co-resident)
  {
    void* args[] = {(void*)&hprep0, (void*)&hprep1, (void*)&hbfinal,
                    (void*)&Wprep, (void*)&b_hh, (void*)&xW, (void*)&flags};
    hipLaunchCooperativeKernel((const void*)gru_persist, dim3(256), dim3(256),
                               args, 0, stream);
  }

  // out = h @ W_out^T + b_out
  gemm_bt<0, 0><<<dim3(O_SZ / 128, 1), 256, 0, stream>>>(
      hbfinal, Woutb, b_out, out, B_SZ, O_SZ, H_SZ);
}

// Round 2
// 801.650 us; speedup vs baseline: 1.0844x; 1.0844x over previous
//
#include <hip/hip_runtime.h>
#include <stdint.h>
#include <stddef.h>

// Problem constants
#define S_LEN 128
#define B_SZ  64
#define V_SZ  32000
#define EH    512
#define EO    512
#define H_SZ  1024
#define O_SZ  1024
#define G3    3072   // 3*H

typedef __attribute__((ext_vector_type(8))) short short8;
typedef __attribute__((ext_vector_type(4))) float floatx4;
typedef __attribute__((ext_vector_type(8))) unsigned short ushortx8;
typedef __attribute__((ext_vector_type(4))) unsigned uintx4;

__device__ __forceinline__ unsigned short f2bf(float f) {
  unsigned u = __builtin_bit_cast(unsigned, f);
  u += 0x7FFFu + ((u >> 16) & 1u);   // round-to-nearest-even
  return (unsigned short)(u >> 16);
}
__device__ __forceinline__ float bf2f(unsigned short h) {
  unsigned u = ((unsigned)h) << 16;
  return __builtin_bit_cast(float, u);
}

__device__ __forceinline__ void gld_lds16(const void* g, void* l) {
  __builtin_amdgcn_global_load_lds((const __attribute__((address_space(1))) void*)g,
                                   (__attribute__((address_space(3))) void*)l, 16, 0, 0);
}

// ---------------------------------------------------------------- converts
// Fused fp32->bf16 convert of W2 / W_ih / W_out into ONE contiguous output
// region (W2b | Wihb | Woutb allocated back-to-back, all multiples of 256 B).
__global__ __launch_bounds__(256) void cvt3_bf16(const float* __restrict__ a,
                                                 const float* __restrict__ b,
                                                 const float* __restrict__ c,
                                                 unsigned short* __restrict__ out) {
  const int na4 = (EO * EH) / 4;        // 65536
  const int nb4 = (G3 * EO) / 4;        // 393216
  int i = blockIdx.x * 256 + threadIdx.x;   // grid sized exactly: 720896 total
  const float* src;
  int off;
  if (i < na4)            { src = a; off = i; }
  else if (i < na4 + nb4) { src = b; off = i - na4; }
  else                    { src = c; off = i - na4 - nb4; }
  float4 v = ((const float4*)src)[off];
  ushort4 o;
  o.x = f2bf(v.x); o.y = f2bf(v.y); o.z = f2bf(v.z); o.w = f2bf(v.w);
  ((ushort4*)out)[i] = o;
}

// ------------------------------------------------- W1 [EH][V] -> W1T bf16 [V][EH]
__global__ __launch_bounds__(256) void transpose_w1_bf16(const float* __restrict__ W1,
                                                         unsigned short* __restrict__ W1T) {
  __shared__ unsigned short tile[64][72];   // [v][e], padded
  int t = threadIdx.x;
  int v0 = blockIdx.x * 64;
  int e0 = blockIdx.y * 64;
  for (int i = 0; i < 4; ++i) {
    int e = (t >> 4) + i * 16;
    int v = (t & 15) * 4;
    float4 w = *(const float4*)&W1[(size_t)(e0 + e) * V_SZ + v0 + v];
    tile[v + 0][e] = f2bf(w.x);
    tile[v + 1][e] = f2bf(w.y);
    tile[v + 2][e] = f2bf(w.z);
    tile[v + 3][e] = f2bf(w.w);
  }
  __syncthreads();
  for (int i = 0; i < 2; ++i) {
    int v = (t >> 3) + i * 32;
    int e = (t & 7) * 8;
    ushortx8 o;
    for (int j = 0; j < 8; ++j) o[j] = tile[v][e + j];
    *(ushortx8*)&W1T[(size_t)(v0 + v) * EH + e0 + e] = o;
  }
}

// ------------------------------------------------- gather + b1 + threshold -> emb bf16
__global__ __launch_bounds__(256) void gather_emb(const int* __restrict__ ids,
                                                  const unsigned short* __restrict__ W1T,
                                                  const float* __restrict__ b1,
                                                  unsigned short* __restrict__ emb) {
  int t = threadIdx.x;
  int tok = blockIdx.x * 4 + (t >> 6);
  int lane = t & 63;
  int id = ids[tok];
  ushortx8 w = *(const ushortx8*)&W1T[(size_t)id * EH + lane * 8];
  float4 blo = *(const float4*)&b1[lane * 8];
  float4 bhi = *(const float4*)&b1[lane * 8 + 4];
  float bv[8] = {blo.x, blo.y, blo.z, blo.w, bhi.x, bhi.y, bhi.z, bhi.w};
  ushortx8 o;
  for (int j = 0; j < 8; ++j) {
    float x = bf2f(w[j]) + bv[j];
    x = (x > 1e-6f) ? x : 0.0f;
    o[j] = f2bf(x);
  }
  *(ushortx8*)&emb[(size_t)tok * EH + lane * 8] = o;
}

// ------------------------------------------------- MFMA GEMM, C = act(A @ B^T + bias)
template <int ACT, int OUT_BF16>
__global__ __launch_bounds__(256) void gemm_bt(const unsigned short* __restrict__ A,
                                               const unsigned short* __restrict__ B,
                                               const float* __restrict__ bias,
                                               void* __restrict__ Cout,
                                               int M, int N, int K) {
  __shared__ unsigned short lA[128 * 32];
  __shared__ unsigned short lB[128 * 32];
  int t = threadIdx.x;
  int lane = t & 63;
  int wave = t >> 6;
  int bn = blockIdx.x, bm = blockIdx.y;
  int wm = (wave >> 1) * 64;
  int wn = (wave & 1) * 64;
  floatx4 acc[4][4] = {};

  int arow = t >> 2;
  int acol = (t & 3) * 8;

  int ga0 = bm * 128 + arow;       if (ga0 >= M) ga0 = M - 1;
  int ga1 = bm * 128 + arow + 64;  if (ga1 >= M) ga1 = M - 1;
  const unsigned short* a0 = A + (size_t)ga0 * K + acol;
  const unsigned short* a1 = A + (size_t)ga1 * K + acol;
  const unsigned short* b0 = B + (size_t)(bn * 128 + arow) * K + acol;
  const unsigned short* b1 = B + (size_t)(bn * 128 + arow + 64) * K + acol;
  unsigned short* lA0 = &lA[t * 8];
  unsigned short* lA1 = &lA[t * 8 + 64 * 32];
  unsigned short* lB0 = &lB[t * 8];
  unsigned short* lB1 = &lB[t * 8 + 64 * 32];

  for (int k0 = 0; k0 < K; k0 += 32) {
    __syncthreads();
    gld_lds16(a0 + k0, lA0);
    gld_lds16(a1 + k0, lA1);
    gld_lds16(b0 + k0, lB0);
    gld_lds16(b1 + k0, lB1);
    __syncthreads();
    short8 af[4], bfr[4];
    for (int i = 0; i < 4; ++i)
      af[i] = *(const short8*)&lA[(wm + i * 16 + (lane & 15)) * 32 + (lane >> 4) * 8];
    for (int j = 0; j < 4; ++j)
      bfr[j] = *(const short8*)&lB[(wn + j * 16 + (lane & 15)) * 32 + (lane >> 4) * 8];
    for (int i = 0; i < 4; ++i)
      for (int j = 0; j < 4; ++j)
        acc[i][j] = __builtin_amdgcn_mfma_f32_16x16x32_bf16(af[i], bfr[j], acc[i][j], 0, 0, 0);
  }

  int rowq = (lane >> 4) * 4;
  for (int j = 0; j < 4; ++j) {
    int col = bn * 128 + wn + j * 16 + (lane & 15);
    float bv = bias[col];
    for (int i = 0; i < 4; ++i) {
      int row0 = bm * 128 + wm + i * 16 + rowq;
      for (int r = 0; r < 4; ++r) {
        int row = row0 + r;
        if (row < M) {
          float v = acc[i][j][r] + bv;
          if (ACT) v = (v > 1e-6f) ? v : 0.0f;
          if (OUT_BF16) ((unsigned short*)Cout)[(size_t)row * N + col] = f2bf(v);
          else          ((float*)Cout)[(size_t)row * N + col] = v;
        }
      }
    }
  }
}

// ------------------------------------------------- W_hh fp32 [3H][H] -> Wprep bf16 in
// MFMA-B-fragment order (see gru_persist).
__global__ __launch_bounds__(256) void prep_whh(const float* __restrict__ W_hh,
                                                unsigned short* __restrict__ Wprep) {
  int tid = blockIdx.x * 256 + threadIdx.x;   // 393216 total
  int lane = tid & 63;
  int c = tid >> 6;          // chunk 0..6143
  int cg = c / 96;
  int r  = c % 96;
  int g  = r >> 5;
  int t  = r & 31;
  int row = g * H_SZ + cg * 16 + (lane & 15);
  int k   = t * 32 + (lane >> 4) * 8;
  const float* src = &W_hh[(size_t)row * H_SZ + k];
  float4 v0 = *(const float4*)src;
  float4 v1 = *(const float4*)(src + 4);
  ushortx8 o;
  o[0] = f2bf(v0.x); o[1] = f2bf(v0.y); o[2] = f2bf(v0.z); o[3] = f2bf(v0.w);
  o[4] = f2bf(v1.x); o[5] = f2bf(v1.y); o[6] = f2bf(v1.z); o[7] = f2bf(v1.w);
  ((ushortx8*)Wprep)[tid] = o;
}

// ------------------------------------------------- persistent GRU recurrence
// 256 blocks x 256 threads, cooperative. Block (bg,cg): batches [bg*16,+16),
// h-cols [cg*16,+16), all 3 gates; wave w = K-quarter [w*256,+256).
//
// Barrier (round-2): round-0 skeleton (drain-sync -> arrive -> poll -> release
// sync) with two fixes vs the serialized counter:
//  - arrive: t==0 plain-stores flags[bg][cg]=s+1 (64 PARALLEL dword stores,
//    distinct addresses -> no same-line RMW serialization at the LLC).
//  - detect: WAVE 0 ONLY polls all 64 flags of its bg in ONE coalesced 256-B
//    load per probe, s_sleep(1) backoff between probes (round-1 lesson: poll
//    volume without backoff floods the coherence point and delays the very
//    stores being waited on).
// h is exchanged with sc1 accesses; no __threadfence / cache-wide inv.
// xW loads for step s+1 are issued during the poll window (latency hidden).
__global__ __launch_bounds__(256) void gru_persist(const unsigned short* __restrict__ hprep0,
                                                   unsigned short* __restrict__ hprep1,
                                                   unsigned short* __restrict__ hbfinal,
                                                   const unsigned short* __restrict__ Wprep,
                                                   const float* __restrict__ b_hh,
                                                   const unsigned short* __restrict__ xW,
                                                   unsigned* __restrict__ flags) {
  __shared__ unsigned short lB[96 * 512];   // 98304 B : W_hh slice, fragment order
  __shared__ float lgh[3][4][256];          // 12288 B : per-wave K-partials
  int t = threadIdx.x;
  int lane = t & 63;
  int w = t >> 6;
  int bg = blockIdx.x >> 6;    // 0..3
  int cg = blockIdx.x & 63;    // 0..63

  // stage W_hh slice once (identity copy, 98 KB)
  const unsigned short* wsrc = Wprep + (size_t)cg * 96 * 512;
  for (int i = 0; i < 24; ++i) {
    int c = w * 24 + i;
    gld_lds16(wsrc + (size_t)c * 512 + lane * 8, &lB[c * 512 + lane * 8]);
  }

  // per-thread update-element constants
  int b_loc = t >> 4;
  int j_loc = t & 15;
  int jcol = cg * 16 + j_loc;          // h column
  int bglob = bg * 16 + b_loc;         // batch
  float bhr = b_hh[jcol];
  float bhz = b_hh[H_SZ + jcol];
  float bhn = b_hh[2 * H_SZ + jcol];
  // scatter-store position for h_new (A-fragment layout); lane pairs (jj even/odd)
  // pack 2 bf16 into one dword store.
  int tt2 = jcol >> 5;
  int q   = (jcol >> 3) & 3;
  int jj  = jcol & 7;
  int Ls  = b_loc | (q << 4);
  size_t hw_off32 = ((((size_t)(bg * 32 + tt2) * 64 + Ls) * 8) + (jj & ~1)) >> 1;

  // flag layout: flags[bg*64 + cg], u32 each (1 KiB used)
  unsigned* fstore = flags + bg * 64 + cg;
  const unsigned* fpoll = flags + bg * 64 + lane;   // wave 0: lane -> cg'

  float hmaster = 0.0f;                // fp32 master h for my (batch, col)
  const unsigned short* hbufs[2] = {hprep0, hprep1};
  __syncthreads();   // drains staging vmcnt

  // xW for s=0
  float xr, xz, xn;
  {
    const unsigned short* xs = xW + (size_t)bglob * G3;
    xr = bf2f(xs[jcol]);
    xz = bf2f(xs[H_SZ + jcol]);
    xn = bf2f(xs[2 * H_SZ + jcol]);
  }

  for (int s = 0; s < S_LEN; ++s) {
    const unsigned short* hr = hbufs[s & 1];
    unsigned* hw32 = (unsigned*)hbufs[(s + 1) & 1];

    // A-fragments for my K-quarter: 8 x 16B coherent (sc1) loads, pipelined,
    // one tied waitcnt. Bypasses stale L1/L2 without any cache-wide inv.
    uintx4 av[8];
#pragma unroll
    for (int i = 0; i < 8; ++i) {
      int tt = w * 8 + i;
      const void* ap = hr + ((size_t)(bg * 32 + tt) * 64 + lane) * 8;
      asm volatile("global_load_dwordx4 %0, %1, off sc1" : "=v"(av[i]) : "v"(ap));
    }
    asm volatile("s_waitcnt vmcnt(0)"
                 : "+v"(av[0]), "+v"(av[1]), "+v"(av[2]), "+v"(av[3]),
                   "+v"(av[4]), "+v"(av[5]), "+v"(av[6]), "+v"(av[7])
                 :: "memory");

    floatx4 acc[3] = {};
#pragma unroll
    for (int i = 0; i < 8; ++i) {
      int tt = w * 8 + i;
      short8 a = __builtin_bit_cast(short8, av[i]);
#pragma unroll
      for (int g = 0; g < 3; ++g) {
        short8 bfr = *(const short8*)&lB[((g * 32 + tt) * 64 + lane) * 8];
        acc[g] = __builtin_amdgcn_mfma_f32_16x16x32_bf16(a, bfr, acc[g], 0, 0, 0);
      }
    }
#pragma unroll
    for (int g = 0; g < 3; ++g)
#pragma unroll
      for (int r = 0; r < 4; ++r)
        lgh[g][w][((lane >> 4) * 4 + r) * 16 + (lane & 15)] = acc[g][r];
    __syncthreads();

    // gate update for my element (sum 4 K-partials)
    float ghr = lgh[0][0][t] + lgh[0][1][t] + lgh[0][2][t] + lgh[0][3][t] + bhr;
    float ghz = lgh[1][0][t] + lgh[1][1][t] + lgh[1][2][t] + lgh[1][3][t] + bhz;
    float ghn = lgh[2][0][t] + lgh[2][1][t] + lgh[2][2][t] + lgh[2][3][t] + bhn;
    float rr = 1.0f / (1.0f + __expf(-(xr + ghr)));
    float zz = 1.0f / (1.0f + __expf(-(xz + ghz)));
    float nn = tanhf(xn + rr * ghn);
    float hnew = (1.0f - zz) * nn + zz * hmaster;
    hmaster = hnew;

    unsigned hb = (unsigned)f2bf(hnew);
    unsigned other = (unsigned)__shfl_xor((int)hb, 1);
    if ((jj & 1) == 0) {
      unsigned packed = hb | (other << 16);   // (jj, jj+1)
      __hip_atomic_store(hw32 + hw_off32, packed,
                         __ATOMIC_RELAXED, __HIP_MEMORY_SCOPE_AGENT);
    }
    if (s == S_LEN - 1) hbfinal[(size_t)bglob * H_SZ + jcol] = (unsigned short)hb;

    if (s < S_LEN - 1) {
      __syncthreads();   // waitcnt vmcnt(0) + barrier: all block h-stores at LLC
      // arrive: parallel per-block flag store (no atomic RMW, no contention)
      if (t == 0)
        __hip_atomic_store(fstore, (unsigned)(s + 1),
                           __ATOMIC_RELAXED, __HIP_MEMORY_SCOPE_AGENT);
      // prefetch next-step xW during the poll window
      {
        const unsigned short* xs = xW + (size_t)(s + 1) * B_SZ * G3 + (size_t)bglob * G3;
        xr = bf2f(xs[jcol]);
        xz = bf2f(xs[H_SZ + jcol]);
        xn = bf2f(xs[2 * H_SZ + jcol]);
      }
      // detect: wave 0 polls all 64 bg-flags (one coalesced 256-B load per
      // probe), s_sleep backoff; lanes exit via exec-mask as they satisfy.
      if (w == 0) {
        unsigned tgt = (unsigned)(s + 1);
        while (__hip_atomic_load(fpoll, __ATOMIC_RELAXED,
                                 __HIP_MEMORY_SCOPE_AGENT) < tgt)
          __builtin_amdgcn_s_sleep(1);
      }
      __syncthreads();   // release
    }
  }
}

// ----------------------------------------------------------------- launch
extern "C" void kernel_launch(void* const* d_in, const int* in_sizes, int n_in,
                              void* d_out, int out_size, void* d_ws, size_t ws_size,
                              hipStream_t stream) {
  const int*   ids   = (const int*)d_in[0];
  const float* W1    = (const float*)d_in[1];
  const float* b1    = (const float*)d_in[2];
  const float* W2    = (const float*)d_in[3];
  const float* b2    = (const float*)d_in[4];
  const float* W_ih  = (const float*)d_in[5];
  const float* b_ih  = (const float*)d_in[6];
  const float* W_hh  = (const float*)d_in[7];
  const float* b_hh  = (const float*)d_in[8];
  const float* W_out = (const float*)d_in[9];
  const float* b_out = (const float*)d_in[10];
  float* out = (float*)d_out;

  uint8_t* wsp = (uint8_t*)d_ws;
  auto alloc = [&](size_t bytes) {
    uint8_t* p = wsp;
    wsp += (bytes + 255) & ~(size_t)255;
    return p;
  };
  unsigned short* W1T   = (unsigned short*)alloc((size_t)V_SZ * EH * 2);
  // NOTE: W2b/Wihb/Woutb must stay contiguous & in this order (cvt3_bf16 fuses
  // all three converts into one launch over the concatenated region).
  unsigned short* W2b   = (unsigned short*)alloc((size_t)EO * EH * 2);
  unsigned short* Wihb  = (unsigned short*)alloc((size_t)G3 * EO * 2);
  unsigned short* Woutb = (unsigned short*)alloc((size_t)O_SZ * H_SZ * 2);
  unsigned short* Wprep = (unsigned short*)alloc((size_t)G3 * H_SZ * 2);
  unsigned short* emb   = (unsigned short*)alloc((size_t)S_LEN * B_SZ * EH * 2);
  unsigned short* x     = (unsigned short*)alloc((size_t)S_LEN * B_SZ * EO * 2);
  unsigned short* xW    = (unsigned short*)alloc((size_t)S_LEN * B_SZ * G3 * 2);
  unsigned short* hprep0 = (unsigned short*)alloc((size_t)B_SZ * H_SZ * 2);
  unsigned short* hprep1 = (unsigned short*)alloc((size_t)B_SZ * H_SZ * 2);
  unsigned short* hbfinal = (unsigned short*)alloc((size_t)B_SZ * H_SZ * 2);
  unsigned*       flags   = (unsigned*)alloc(4096);   // [4 bg][64 cg] u32 (1 KiB used)

  // fused weight converts (fp32 -> bf16): W2 | W_ih | W_out -> one launch
  cvt3_bf16<<<dim3(2816), 256, 0, stream>>>(W2, W_ih, W_out, W2b);

  // W_hh -> MFMA-fragment-ordered bf16
  prep_whh<<<dim3(1536), 256, 0, stream>>>(W_hh, Wprep);

  // zero h0 (fragment-layout buffer read at s=0) and the flag array
  hipMemsetAsync(hprep0, 0, (size_t)B_SZ * H_SZ * 2, stream);
  hipMemsetAsync(flags, 0, 4096, stream);

  // W1 transpose -> bf16
  transpose_w1_bf16<<<dim3(V_SZ / 64, EH / 64), 256, 0, stream>>>(W1, W1T);

  // embedding gather + b1 + threshold
  gather_emb<<<dim3(S_LEN * B_SZ / 4), 256, 0, stream>>>(ids, W1T, b1, emb);

  // x = thresh(emb @ W2^T + b2)
  gemm_bt<1, 1><<<dim3(EO / 128, S_LEN * B_SZ / 128), 256, 0, stream>>>(
      emb, W2b, b2, x, S_LEN * B_SZ, EO, EH);

  // xW = x @ W_ih^T + b_ih
  gemm_bt<0, 1><<<dim3(G3 / 128, S_LEN * B_SZ / 128), 256, 0, stream>>>(
      x, Wihb, b_ih, xW, S_LEN * B_SZ, G3, EO);

  // persistent GRU recurrence (cooperative: all 256 blocks co-resident)
  {
    void* args[] = {(void*)&hprep0, (void*)&hprep1, (void*)&hbfinal,
                    (void*)&Wprep, (void*)&b_hh, (void*)&xW, (void*)&flags};
    hipLaunchCooperativeKernel((const void*)gru_persist, dim3(256), dim3(256),
                               args, 0, stream);
  }

  // out = h @ W_out^T + b_out
  gemm_bt<0, 0><<<dim3(O_SZ / 128, 1), 256, 0, stream>>>(
      hbfinal, Woutb, b_out, out, B_SZ, O_SZ, H_SZ);
}

// Round 3
// 652.523 us; speedup vs baseline: 1.3322x; 1.2285x over previous
//
#include <hip/hip_runtime.h>
#include <stdint.h>
#include <stddef.h>

// Problem constants
#define S_LEN 128
#define B_SZ  64
#define V_SZ  32000
#define EH    512
#define EO    512
#define H_SZ  1024
#define O_SZ  1024
#define G3    3072   // 3*H

typedef __attribute__((ext_vector_type(8))) short short8;
typedef __attribute__((ext_vector_type(4))) float floatx4;
typedef __attribute__((ext_vector_type(8))) unsigned short ushortx8;
typedef __attribute__((ext_vector_type(4))) unsigned uintx4;

__device__ __forceinline__ unsigned short f2bf(float f) {
  unsigned u = __builtin_bit_cast(unsigned, f);
  u += 0x7FFFu + ((u >> 16) & 1u);   // round-to-nearest-even
  return (unsigned short)(u >> 16);
}
__device__ __forceinline__ float bf2f(unsigned short h) {
  unsigned u = ((unsigned)h) << 16;
  return __builtin_bit_cast(float, u);
}

__device__ __forceinline__ void gld_lds16(const void* g, void* l) {
  __builtin_amdgcn_global_load_lds((const __attribute__((address_space(1))) void*)g,
                                   (__attribute__((address_space(3))) void*)l, 16, 0, 0);
}

// ---------------------------------------------------------------- converts
// Fused fp32->bf16 convert of W2 / W_ih / W_out into ONE contiguous output
// region (W2b | Wihb | Woutb allocated back-to-back, all multiples of 256 B).
__global__ __launch_bounds__(256) void cvt3_bf16(const float* __restrict__ a,
                                                 const float* __restrict__ b,
                                                 const float* __restrict__ c,
                                                 unsigned short* __restrict__ out) {
  const int na4 = (EO * EH) / 4;        // 65536
  const int nb4 = (G3 * EO) / 4;        // 393216
  int i = blockIdx.x * 256 + threadIdx.x;   // grid sized exactly: 720896 total
  const float* src;
  int off;
  if (i < na4)            { src = a; off = i; }
  else if (i < na4 + nb4) { src = b; off = i - na4; }
  else                    { src = c; off = i - na4 - nb4; }
  float4 v = ((const float4*)src)[off];
  ushort4 o;
  o.x = f2bf(v.x); o.y = f2bf(v.y); o.z = f2bf(v.z); o.w = f2bf(v.w);
  ((ushort4*)out)[i] = o;
}

// ------------------------------------------------- W1 [EH][V] -> W1T bf16 [V][EH]
__global__ __launch_bounds__(256) void transpose_w1_bf16(const float* __restrict__ W1,
                                                         unsigned short* __restrict__ W1T) {
  __shared__ unsigned short tile[64][72];   // [v][e], padded
  int t = threadIdx.x;
  int v0 = blockIdx.x * 64;
  int e0 = blockIdx.y * 64;
  for (int i = 0; i < 4; ++i) {
    int e = (t >> 4) + i * 16;
    int v = (t & 15) * 4;
    float4 w = *(const float4*)&W1[(size_t)(e0 + e) * V_SZ + v0 + v];
    tile[v + 0][e] = f2bf(w.x);
    tile[v + 1][e] = f2bf(w.y);
    tile[v + 2][e] = f2bf(w.z);
    tile[v + 3][e] = f2bf(w.w);
  }
  __syncthreads();
  for (int i = 0; i < 2; ++i) {
    int v = (t >> 3) + i * 32;
    int e = (t & 7) * 8;
    ushortx8 o;
    for (int j = 0; j < 8; ++j) o[j] = tile[v][e + j];
    *(ushortx8*)&W1T[(size_t)(v0 + v) * EH + e0 + e] = o;
  }
}

// ------------------------------------------------- gather + b1 + threshold -> emb bf16
__global__ __launch_bounds__(256) void gather_emb(const int* __restrict__ ids,
                                                  const unsigned short* __restrict__ W1T,
                                                  const float* __restrict__ b1,
                                                  unsigned short* __restrict__ emb) {
  int t = threadIdx.x;
  int tok = blockIdx.x * 4 + (t >> 6);
  int lane = t & 63;
  int id = ids[tok];
  ushortx8 w = *(const ushortx8*)&W1T[(size_t)id * EH + lane * 8];
  float4 blo = *(const float4*)&b1[lane * 8];
  float4 bhi = *(const float4*)&b1[lane * 8 + 4];
  float bv[8] = {blo.x, blo.y, blo.z, blo.w, bhi.x, bhi.y, bhi.z, bhi.w};
  ushortx8 o;
  for (int j = 0; j < 8; ++j) {
    float x = bf2f(w[j]) + bv[j];
    x = (x > 1e-6f) ? x : 0.0f;
    o[j] = f2bf(x);
  }
  *(ushortx8*)&emb[(size_t)tok * EH + lane * 8] = o;
}

// ------------------------------------------------- MFMA GEMM, C = act(A @ B^T + bias)
// BK=64 + T2 XOR-swizzled LDS (16-B slots, slot ^= row&7):
//  - half the barriers/drains of the BK=32 version (32 MFMA per staging round)
//  - ds_read_b128 fragment reads spread over all 32 banks (2-way = free)
//  - LDS dest of global_load_lds stays LINEAR; the swizzle is applied by
//    permuting the per-thread GLOBAL source slot (guide §5 rule 21).
template <int ACT, int OUT_BF16>
__global__ __launch_bounds__(256) void gemm_bt(const unsigned short* __restrict__ A,
                                               const unsigned short* __restrict__ B,
                                               const float* __restrict__ bias,
                                               void* __restrict__ Cout,
                                               int M, int N, int K) {
  __shared__ unsigned short lA[128 * 64];   // 16 KB, [row][slot^ (row&7)] 16-B slots
  __shared__ unsigned short lB[128 * 64];   // 16 KB
  int t = threadIdx.x;
  int lane = t & 63;
  int wave = t >> 6;
  int bn = blockIdx.x, bm = blockIdx.y;
  int wm = (wave >> 1) * 64;
  int wn = (wave & 1) * 64;
  floatx4 acc[4][4] = {};

  // staging: pass p covers rows [p*32, p*32+32); thread t -> row p*32+(t>>3),
  // physical slot t&7 (LDS linear dest), logical slot (t&7)^((t>>3)&7).
  int srow = t >> 3;                       // 0..31 within pass
  int sslot = (t & 7) ^ (srow & 7);        // logical (global) 16-B slot
  int scol = sslot * 8;                    // element offset within BK=64

  const unsigned short* aptr[4];
  const unsigned short* bptr[4];
#pragma unroll
  for (int p = 0; p < 4; ++p) {
    int gra = bm * 128 + p * 32 + srow;  if (gra >= M) gra = M - 1;
    aptr[p] = A + (size_t)gra * K + scol;
    bptr[p] = B + (size_t)(bn * 128 + p * 32 + srow) * K + scol;
  }

  for (int k0 = 0; k0 < K; k0 += 64) {
    __syncthreads();
#pragma unroll
    for (int p = 0; p < 4; ++p) {
      gld_lds16(aptr[p] + k0, &lA[p * 2048 + t * 8]);
      gld_lds16(bptr[p] + k0, &lB[p * 2048 + t * 8]);
    }
    __syncthreads();
#pragma unroll
    for (int kk = 0; kk < 2; ++kk) {
      short8 af[4], bfr[4];
#pragma unroll
      for (int i = 0; i < 4; ++i) {
        int row = wm + i * 16 + (lane & 15);
        int phys = (kk * 4 + (lane >> 4)) ^ (row & 7);
        af[i] = *(const short8*)&lA[row * 64 + phys * 8];
      }
#pragma unroll
      for (int j = 0; j < 4; ++j) {
        int row = wn + j * 16 + (lane & 15);
        int phys = (kk * 4 + (lane >> 4)) ^ (row & 7);
        bfr[j] = *(const short8*)&lB[row * 64 + phys * 8];
      }
#pragma unroll
      for (int i = 0; i < 4; ++i)
#pragma unroll
        for (int j = 0; j < 4; ++j)
          acc[i][j] = __builtin_amdgcn_mfma_f32_16x16x32_bf16(af[i], bfr[j], acc[i][j], 0, 0, 0);
    }
  }

  int rowq = (lane >> 4) * 4;
  for (int j = 0; j < 4; ++j) {
    int col = bn * 128 + wn + j * 16 + (lane & 15);
    float bv = bias[col];
    for (int i = 0; i < 4; ++i) {
      int row0 = bm * 128 + wm + i * 16 + rowq;
      for (int r = 0; r < 4; ++r) {
        int row = row0 + r;
        if (row < M) {
          float v = acc[i][j][r] + bv;
          if (ACT) v = (v > 1e-6f) ? v : 0.0f;
          if (OUT_BF16) ((unsigned short*)Cout)[(size_t)row * N + col] = f2bf(v);
          else          ((float*)Cout)[(size_t)row * N + col] = v;
        }
      }
    }
  }
}

// ------------------------------------------------- W_hh fp32 [3H][H] -> Wprep bf16 in
// MFMA-B-fragment order (see gru_persist).
__global__ __launch_bounds__(256) void prep_whh(const float* __restrict__ W_hh,
                                                unsigned short* __restrict__ Wprep) {
  int tid = blockIdx.x * 256 + threadIdx.x;   // 393216 total
  int lane = tid & 63;
  int c = tid >> 6;          // chunk 0..6143
  int cg = c / 96;
  int r  = c % 96;
  int g  = r >> 5;
  int t  = r & 31;
  int row = g * H_SZ + cg * 16 + (lane & 15);
  int k   = t * 32 + (lane >> 4) * 8;
  const float* src = &W_hh[(size_t)row * H_SZ + k];
  float4 v0 = *(const float4*)src;
  float4 v1 = *(const float4*)(src + 4);
  ushortx8 o;
  o[0] = f2bf(v0.x); o[1] = f2bf(v0.y); o[2] = f2bf(v0.z); o[3] = f2bf(v0.w);
  o[4] = f2bf(v1.x); o[5] = f2bf(v1.y); o[6] = f2bf(v1.z); o[7] = f2bf(v1.w);
  ((ushortx8*)Wprep)[tid] = o;
}

// ------------------------------------------------- persistent GRU recurrence
// 256 blocks x 256 threads, cooperative. Block (bg,cg): batches [bg*16,+16),
// h-cols [cg*16,+16), all 3 gates; wave w = K-quarter [w*256,+256).
// EXACT round-0 form (measured 3.0 us/step): per-bg monotonic fetch_add
// counter, single-lane s_sleep(2) poll, drain-sync before arrive, release
// sync after. Rounds 1-2 (per-wave flags / parallel flags + wave-wide poll)
// both regressed -- this barrier is a measured local optimum; do not touch.
__global__ __launch_bounds__(256) void gru_persist(const unsigned short* __restrict__ hprep0,
                                                   unsigned short* __restrict__ hprep1,
                                                   unsigned short* __restrict__ hbfinal,
                                                   const unsigned short* __restrict__ Wprep,
                                                   const float* __restrict__ b_hh,
                                                   const unsigned short* __restrict__ xW,
                                                   unsigned* __restrict__ bar) {
  __shared__ unsigned short lB[96 * 512];   // 98304 B : W_hh slice, fragment order
  __shared__ float lgh[3][4][256];          // 12288 B : per-wave K-partials
  __shared__ float lhf[256];                //  1024 B : fp32 master h slice
  int t = threadIdx.x;
  int lane = t & 63;
  int w = t >> 6;
  int bg = blockIdx.x >> 6;    // 0..3
  int cg = blockIdx.x & 63;    // 0..63

  // stage W_hh slice once (identity copy, 98 KB)
  const unsigned short* wsrc = Wprep + (size_t)cg * 96 * 512;
  for (int i = 0; i < 24; ++i) {
    int c = w * 24 + i;
    gld_lds16(wsrc + (size_t)c * 512 + lane * 8, &lB[c * 512 + lane * 8]);
  }
  lhf[t] = 0.0f;

  // per-thread update-element constants
  int b_loc = t >> 4;
  int j_loc = t & 15;
  int jcol = cg * 16 + j_loc;          // h column
  int bglob = bg * 16 + b_loc;         // batch
  float bhr = b_hh[jcol];
  float bhz = b_hh[H_SZ + jcol];
  float bhn = b_hh[2 * H_SZ + jcol];
  // scatter-store position for h_new (A-fragment layout); lane pairs (jj even/odd)
  // pack 2 bf16 into one dword store.
  int tt2 = jcol >> 5;
  int q   = (jcol >> 3) & 3;
  int jj  = jcol & 7;
  int Ls  = b_loc | (q << 4);
  size_t hw_off32 = ((((size_t)(bg * 32 + tt2) * 64 + Ls) * 8) + (jj & ~1)) >> 1;

  const unsigned short* hbufs[2] = {hprep0, hprep1};
  unsigned* barp = bar + bg * 64;      // per-bg counter, 256 B apart
  __syncthreads();   // drains staging vmcnt

  for (int s = 0; s < S_LEN; ++s) {
    const unsigned short* hr = hbufs[s & 1];
    unsigned* hw32 = (unsigned*)hbufs[(s + 1) & 1];

    // A-fragments for my K-quarter: 8 x 16B coherent (sc1) loads, pipelined,
    // one tied waitcnt. Bypasses stale L1/L2 without any cache-wide inv.
    uintx4 av[8];
#pragma unroll
    for (int i = 0; i < 8; ++i) {
      int tt = w * 8 + i;
      const void* ap = hr + ((size_t)(bg * 32 + tt) * 64 + lane) * 8;
      asm volatile("global_load_dwordx4 %0, %1, off sc1" : "=v"(av[i]) : "v"(ap));
    }
    // xw loads (plain cached; produced before kernel launch)
    const unsigned short* xs = xW + (size_t)s * B_SZ * G3 + (size_t)bglob * G3;
    float xr = bf2f(xs[jcol]);
    float xz = bf2f(xs[H_SZ + jcol]);
    float xn = bf2f(xs[2 * H_SZ + jcol]);
    asm volatile("s_waitcnt vmcnt(0)"
                 : "+v"(av[0]), "+v"(av[1]), "+v"(av[2]), "+v"(av[3]),
                   "+v"(av[4]), "+v"(av[5]), "+v"(av[6]), "+v"(av[7])
                 :: "memory");

    floatx4 acc[3] = {};
#pragma unroll
    for (int i = 0; i < 8; ++i) {
      int tt = w * 8 + i;
      short8 a = __builtin_bit_cast(short8, av[i]);
#pragma unroll
      for (int g = 0; g < 3; ++g) {
        short8 bfr = *(const short8*)&lB[((g * 32 + tt) * 64 + lane) * 8];
        acc[g] = __builtin_amdgcn_mfma_f32_16x16x32_bf16(a, bfr, acc[g], 0, 0, 0);
      }
    }
#pragma unroll
    for (int g = 0; g < 3; ++g)
#pragma unroll
      for (int r = 0; r < 4; ++r)
        lgh[g][w][((lane >> 4) * 4 + r) * 16 + (lane & 15)] = acc[g][r];
    __syncthreads();

    // gate update for my element (sum 4 K-partials)
    float ghr = lgh[0][0][t] + lgh[0][1][t] + lgh[0][2][t] + lgh[0][3][t] + bhr;
    float ghz = lgh[1][0][t] + lgh[1][1][t] + lgh[1][2][t] + lgh[1][3][t] + bhz;
    float ghn = lgh[2][0][t] + lgh[2][1][t] + lgh[2][2][t] + lgh[2][3][t] + bhn;
    float rr = 1.0f / (1.0f + __expf(-(xr + ghr)));
    float zz = 1.0f / (1.0f + __expf(-(xz + ghz)));
    float nn = tanhf(xn + rr * ghn);
    float ho = lhf[t];
    float hnew = (1.0f - zz) * nn + zz * ho;
    lhf[t] = hnew;

    unsigned hb = (unsigned)f2bf(hnew);
    unsigned other = (unsigned)__shfl_xor((int)hb, 1);
    if ((jj & 1) == 0) {
      unsigned packed = hb | (other << 16);   // (jj, jj+1)
      __hip_atomic_store(hw32 + hw_off32, packed,
                         __ATOMIC_RELAXED, __HIP_MEMORY_SCOPE_AGENT);
    }
    if (s == S_LEN - 1) hbfinal[(size_t)bglob * H_SZ + jcol] = (unsigned short)hb;

    if (s < S_LEN - 1) {
      __syncthreads();   // waitcnt vmcnt(0) + barrier: all block h-stores at L3
      if (t == 0) {
        __hip_atomic_fetch_add(barp, 1u, __ATOMIC_RELAXED, __HIP_MEMORY_SCOPE_AGENT);
        unsigned target = 64u * (unsigned)(s + 1);
        while (__hip_atomic_load(barp, __ATOMIC_RELAXED, __HIP_MEMORY_SCOPE_AGENT) < target)
          __builtin_amdgcn_s_sleep(2);
      }
      __syncthreads();
    }
  }
}

// ----------------------------------------------------------------- launch
extern "C" void kernel_launch(void* const* d_in, const int* in_sizes, int n_in,
                              void* d_out, int out_size, void* d_ws, size_t ws_size,
                              hipStream_t stream) {
  const int*   ids   = (const int*)d_in[0];
  const float* W1    = (const float*)d_in[1];
  const float* b1    = (const float*)d_in[2];
  const float* W2    = (const float*)d_in[3];
  const float* b2    = (const float*)d_in[4];
  const float* W_ih  = (const float*)d_in[5];
  const float* b_ih  = (const float*)d_in[6];
  const float* W_hh  = (const float*)d_in[7];
  const float* b_hh  = (const float*)d_in[8];
  const float* W_out = (const float*)d_in[9];
  const float* b_out = (const float*)d_in[10];
  float* out = (float*)d_out;

  uint8_t* wsp = (uint8_t*)d_ws;
  auto alloc = [&](size_t bytes) {
    uint8_t* p = wsp;
    wsp += (bytes + 255) & ~(size_t)255;
    return p;
  };
  unsigned short* W1T   = (unsigned short*)alloc((size_t)V_SZ * EH * 2);
  // NOTE: W2b/Wihb/Woutb must stay contiguous & in this order (cvt3_bf16 fuses
  // all three converts into one launch over the concatenated region).
  unsigned short* W2b   = (unsigned short*)alloc((size_t)EO * EH * 2);
  unsigned short* Wihb  = (unsigned short*)alloc((size_t)G3 * EO * 2);
  unsigned short* Woutb = (unsigned short*)alloc((size_t)O_SZ * H_SZ * 2);
  unsigned short* Wprep = (unsigned short*)alloc((size_t)G3 * H_SZ * 2);
  unsigned short* emb   = (unsigned short*)alloc((size_t)S_LEN * B_SZ * EH * 2);
  unsigned short* x     = (unsigned short*)alloc((size_t)S_LEN * B_SZ * EO * 2);
  unsigned short* xW    = (unsigned short*)alloc((size_t)S_LEN * B_SZ * G3 * 2);
  unsigned short* hprep0 = (unsigned short*)alloc((size_t)B_SZ * H_SZ * 2);
  unsigned short* hprep1 = (unsigned short*)alloc((size_t)B_SZ * H_SZ * 2);
  unsigned short* hbfinal = (unsigned short*)alloc((size_t)B_SZ * H_SZ * 2);
  unsigned*       bar     = (unsigned*)alloc(1024);

  // fused weight converts (fp32 -> bf16): W2 | W_ih | W_out -> one launch
  cvt3_bf16<<<dim3(2816), 256, 0, stream>>>(W2, W_ih, W_out, W2b);

  // W_hh -> MFMA-fragment-ordered bf16
  prep_whh<<<dim3(1536), 256, 0, stream>>>(W_hh, Wprep);

  // zero h0 (fragment-layout buffer read at s=0) and the 4 barrier counters
  hipMemsetAsync(hprep0, 0, (size_t)B_SZ * H_SZ * 2, stream);
  hipMemsetAsync(bar, 0, 1024, stream);

  // W1 transpose -> bf16
  transpose_w1_bf16<<<dim3(V_SZ / 64, EH / 64), 256, 0, stream>>>(W1, W1T);

  // embedding gather + b1 + threshold
  gather_emb<<<dim3(S_LEN * B_SZ / 4), 256, 0, stream>>>(ids, W1T, b1, emb);

  // x = thresh(emb @ W2^T + b2)
  gemm_bt<1, 1><<<dim3(EO / 128, S_LEN * B_SZ / 128), 256, 0, stream>>>(
      emb, W2b, b2, x, S_LEN * B_SZ, EO, EH);

  // xW = x @ W_ih^T + b_ih
  gemm_bt<0, 1><<<dim3(G3 / 128, S_LEN * B_SZ / 128), 256, 0, stream>>>(
      x, Wihb, b_ih, xW, S_LEN * B_SZ, G3, EO);

  // persistent GRU recurrence (cooperative: all 256 blocks co-resident)
  {
    void* args[] = {(void*)&hprep0, (void*)&hprep1, (void*)&hbfinal,
                    (void*)&Wprep, (void*)&b_hh, (void*)&xW, (void*)&bar};
    hipLaunchCooperativeKernel((const void*)gru_persist, dim3(256), dim3(256),
                               args, 0, stream);
  }

  // out = h @ W_out^T + b_out
  gemm_bt<0, 0><<<dim3(O_SZ / 128, 1), 256, 0, stream>>>(
      hbfinal, Woutb, b_out, out, B_SZ, O_SZ, H_SZ);
}